// Round 5
// baseline (420.385 us; speedup 1.0000x reference)
//
#include <hip/hip_runtime.h>
#include <hip/hip_bf16.h>

// Problem constants (from reference)
#define N_NODES 50000
#define N_REL   8
#define DIM     128      // IN_DIM == HID == 128
#define N_EDGES 800000
#define N_TRIP  100000
#define NSEG    (N_NODES * N_REL)   // 400000
#define NBUCKET 196                 // ceil(50000/256) dst buckets
#define CAP     6144                // slack slots per bucket (mean 4082)

typedef __attribute__((ext_vector_type(8))) short bf16x8;
typedef __attribute__((ext_vector_type(4))) float f32x4;

static __device__ __forceinline__ unsigned short f2b(float f) {
    __hip_bfloat16 h = __float2bfloat16(f);
    return *reinterpret_cast<unsigned short*>(&h);
}
static __device__ __forceinline__ float blo(unsigned int u) {
    return __uint_as_float(u << 16);
}
static __device__ __forceinline__ float bhi(unsigned int u) {
    return __uint_as_float(u & 0xffff0000u);
}

// ---------------------------------------------------------------------------
// bucket_scatter: bin edges by dst>>8 into fixed-capacity slack regions.
// packed word: src[0:16) | rel[16:19) | dstLow[19:27)   (R0's proven kernel)
__global__ __launch_bounds__(256) void bucket_scatter(
        const int* __restrict__ edge_index,
        const int* __restrict__ edge_type,
        int* __restrict__ gcnt,
        unsigned int* __restrict__ slack) {
    __shared__ int hist[NBUCKET];
    __shared__ int cur[NBUCKET];
    int tid = threadIdx.x;
    for (int i = tid; i < NBUCKET; i += 256) hist[i] = 0;
    __syncthreads();
    int base = blockIdx.x * 4096;
    unsigned int w[16];
    int bk[16];
    #pragma unroll
    for (int i = 0; i < 16; ++i) {
        int e = base + i * 256 + tid;
        if (e < N_EDGES) {
            int src = edge_index[e];
            int dst = edge_index[N_EDGES + e];
            int r = edge_type[e];
            w[i] = (unsigned int)src | ((unsigned int)r << 16) |
                   ((unsigned int)(dst & 255) << 19);
            bk[i] = dst >> 8;
            atomicAdd(&hist[bk[i]], 1);
        } else {
            bk[i] = -1;
        }
    }
    __syncthreads();
    for (int i = tid; i < NBUCKET; i += 256)
        cur[i] = atomicAdd(&gcnt[i], hist[i]);
    __syncthreads();
    #pragma unroll
    for (int i = 0; i < 16; ++i) {
        if (bk[i] >= 0) {
            int p = atomicAdd(&cur[bk[i]], 1);
            if (p < CAP) slack[(size_t)bk[i] * CAP + p] = w[i];
        }
    }
}

// ---------------------------------------------------------------------------
// bucket_scan: exclusive scan of 196 bucket counts; also set sentinel.
__global__ void bucket_scan(const int* __restrict__ gcnt,
                            int* __restrict__ gbase,
                            int* __restrict__ offsets) {
    __shared__ int sh[256];
    int t = threadIdx.x;
    int v = (t < NBUCKET) ? gcnt[t] : 0;
    sh[t] = v;
    __syncthreads();
    #pragma unroll
    for (int off = 1; off < 256; off <<= 1) {
        int x = (t >= off) ? sh[t - off] : 0;
        __syncthreads();
        sh[t] += x;
        __syncthreads();
    }
    if (t < NBUCKET) gbase[t] = sh[t] - v;
    if (t == 0) offsets[NSEG] = N_EDGES;
}

// ---------------------------------------------------------------------------
// bucket_sort: one block per bucket. LDS counting sort over 2048 local segs
// (dstLow*8+rel). Writes sorted_pack (FULL word: src|rel<<16|dstLow<<19)
// and offsets (dst-major). R0's proven kernel, minus invcnt.
__global__ __launch_bounds__(256) void bucket_sort(
        const unsigned int* __restrict__ slack,
        const int* __restrict__ gcnt,
        const int* __restrict__ gbase,
        unsigned int* __restrict__ sorted_pack,
        int* __restrict__ offsets) {
    __shared__ unsigned int ebuf[CAP];   // 24 KB
    __shared__ unsigned int obuf[CAP];   // 24 KB
    __shared__ int hist[2048];           // 8 KB (later reused as cursor)
    __shared__ int excl[2048];           // 8 KB
    __shared__ int sh[256];
    int b = blockIdx.x, t = threadIdx.x;
    int n = gcnt[b]; if (n > CAP) n = CAP;
    int bb = gbase[b];
    for (int i = t; i < n; i += 256) ebuf[i] = slack[(size_t)b * CAP + i];
    for (int i = t; i < 2048; i += 256) hist[i] = 0;
    __syncthreads();
    for (int i = t; i < n; i += 256) {
        unsigned int w = ebuf[i];
        int seg = (int)((w >> 19) << 3) | (int)((w >> 16) & 7u);
        atomicAdd(&hist[seg], 1);
    }
    __syncthreads();
    // blocked exclusive scan over 2048: thread t owns [t*8, t*8+8)
    int c[8];
    int s = 0;
    #pragma unroll
    for (int j = 0; j < 8; ++j) { c[j] = hist[t * 8 + j]; s += c[j]; }
    sh[t] = s;
    __syncthreads();
    #pragma unroll
    for (int off = 1; off < 256; off <<= 1) {
        int x = (t >= off) ? sh[t - off] : 0;
        __syncthreads();
        sh[t] += x;
        __syncthreads();
    }
    int ex = sh[t] - s;
    #pragma unroll
    for (int j = 0; j < 8; ++j) { excl[t * 8 + j] = ex; ex += c[j]; }
    __syncthreads();
    #pragma unroll
    for (int j = 0; j < 8; ++j) hist[t * 8 + j] = excl[t * 8 + j];  // cursor
    __syncthreads();
    for (int i = t; i < n; i += 256) {
        unsigned int w = ebuf[i];
        int seg = (int)((w >> 19) << 3) | (int)((w >> 16) & 7u);
        int p = atomicAdd(&hist[seg], 1);
        obuf[p] = w;                     // keep full word (src|rel|dstLow)
    }
    __syncthreads();
    for (int i = t; i < n; i += 256) sorted_pack[bb + i] = obuf[i];
    int segbase = b * 2048;
    #pragma unroll
    for (int j = 0; j < 8; ++j) {
        int gseg = segbase + t * 8 + j;
        if (gseg < NSEG) offsets[gseg] = bb + excl[t * 8 + j];
    }
}

// ---------------------------------------------------------------------------
// cvt_emb: fp32 -> bf16, 2 elems/thread (packed)
__global__ void cvt_emb_kernel(const float* __restrict__ src,
                               unsigned short* __restrict__ dst) {
    int i = blockIdx.x * blockDim.x + threadIdx.x;
    const int npair = N_NODES * DIM / 2;
    if (i >= npair) return;
    float2 v = ((const float2*)src)[i];
    unsigned int p = (unsigned int)f2b(v.x) | ((unsigned int)f2b(v.y) << 16);
    ((unsigned int*)dst)[i] = p;
}

// ---------------------------------------------------------------------------
// cvt_w2: Wt2[s][n][k] bf16 for both layers; s=0 -> root, s>=1 -> W_{s-1}.
__global__ void cvt_w2_kernel(const float* __restrict__ root0,
                              const float* __restrict__ W0,
                              const float* __restrict__ root1,
                              const float* __restrict__ W1,
                              unsigned short* __restrict__ Wt2a,
                              unsigned short* __restrict__ Wt2b) {
    int s = blockIdx.x;        // 0..8
    int n = blockIdx.y;        // 0..127
    int k = threadIdx.x;       // 0..127
    const float* root = blockIdx.z ? root1 : root0;
    const float* W    = blockIdx.z ? W1 : W0;
    unsigned short* Wt2 = blockIdx.z ? Wt2b : Wt2a;
    float v = (s == 0) ? root[k * 128 + n]
                       : W[((size_t)(s - 1) * 128 + k) * 128 + n];
    Wt2[((size_t)s * 128 + n) * 128 + k] = f2b(v);
}

// ---------------------------------------------------------------------------
// rgcn_fused v4: block = 16 dsts, 4 waves; wave owns 4 dsts. Dst-major sort
// means each wave streams its dsts' edges over ALL rels as ONE contiguous
// range (~64 edges = 8 unguarded 8-batches, R0's proven gather idiom; no
// per-rel chopping, no per-rel barriers). Flush-on-(dst,rel)-change writes
// bf16 mean rows into a 16x1024 XOR-swizzled LDS tile (K = rel*128+d).
// ONE barrier, then K=1152 MFMA: slot 0 (root, A from global h) was done
// pre-barrier; slots 1..8 read A from LDS. Grid = 3125 (exact, no tails).
#define FLUSH()                                                                \
    do {                                                                       \
        float inv_ = __builtin_amdgcn_rcpf((float)cnt);                        \
        int row_ = curk >> 3;                                                  \
        int c_ = (curk & 7) * 16 + (lane >> 2);                                \
        int swz_ = (c_ & ~7) | ((c_ ^ row_) & 7);                              \
        MtU[row_ * 512 + swz_ * 4 + (lane & 3)] =                              \
            (unsigned int)f2b(a0 * inv_) | ((unsigned int)f2b(a1 * inv_) << 16);\
        flushed |= 1u << (curk & 31);                                          \
    } while (0)

#define CONSUME(w_, v_)                                                        \
    do {                                                                       \
        int k_ = (int)((((w_) >> 19) & 15u) * 8u + (((w_) >> 16) & 7u));       \
        float x0_ = blo(v_), x1_ = bhi(v_);                                    \
        if (k_ != curk) {                                                      \
            if (curk >= 0) FLUSH();                                            \
            curk = k_; a0 = x0_; a1 = x1_; cnt = 1;                            \
        } else { a0 += x0_; a1 += x1_; ++cnt; }                                \
    } while (0)

__global__ __launch_bounds__(256) void rgcn_fused(
        const unsigned short* __restrict__ hb,    // N x 128 bf16
        const unsigned short* __restrict__ Wt2,   // 9 x 128(n) x 128(k) bf16
        const float* __restrict__ bias,           // 128
        const int* __restrict__ offsets,          // NSEG+1, dst-major
        const unsigned int* __restrict__ spack,   // src|rel<<16|dstLow<<19
        unsigned short* __restrict__ hout) {      // N x 128 bf16
    __shared__ unsigned short Mt[16 * 1024];      // 32 KB: row=dstLocal, k=rel*128+d
    unsigned int* MtU = (unsigned int*)Mt;
    const unsigned int* hb32 = (const unsigned int*)hb;

    int tid = threadIdx.x;
    int wid = tid >> 6, lane = tid & 63;
    int quad = lane >> 4, l16 = lane & 15;
    int t0 = blockIdx.x * 16;

    // wave's contiguous edge range: dsts [t0+wid*4, t0+wid*4+4), all rels
    int beg = offsets[(t0 + wid * 4) * 8];
    int end = offsets[(t0 + wid * 4 + 4) * 8];

    // window-0 pack prefetch (in flight under the root MFMA below)
    int m = end - beg; if (m > 64) m = 64;
    unsigned int pk = 0;
    if (lane < m) pk = spack[beg + lane];

    f32x4 acc[2];
    acc[0] = (f32x4){0.f, 0.f, 0.f, 0.f};
    acc[1] = (f32x4){0.f, 0.f, 0.f, 0.f};

    // ---- slot 0: root transform, A-frags direct from global h ----
    {
        const unsigned short* Wp = Wt2 + (size_t)(wid * 32 + l16) * DIM + quad * 8;
        bf16x8 b0[4], b1[4];
        #pragma unroll
        for (int kk = 0; kk < 4; ++kk) {
            b0[kk] = *(const bf16x8*)(Wp + kk * 32);
            b1[kk] = *(const bf16x8*)(Wp + 16 * DIM + kk * 32);
        }
        #pragma unroll
        for (int kk = 0; kk < 4; ++kk) {
            bf16x8 af = *(const bf16x8*)(hb + (size_t)(t0 + l16) * DIM + kk * 32 + quad * 8);
            acc[0] = __builtin_amdgcn_mfma_f32_16x16x32_bf16(af, b0[kk], acc[0], 0, 0, 0);
            acc[1] = __builtin_amdgcn_mfma_f32_16x16x32_bf16(af, b1[kk], acc[1], 0, 0, 0);
        }
    }

    // ---- single uninterrupted gather/aggregate stream ----
    float a0 = 0.f, a1 = 0.f;
    int curk = -1, cnt = 0;
    unsigned int flushed = 0;
    int base = beg;
    while (base < end) {
        int nbase = base + 64;
        unsigned int pkn = 0;
        if (nbase < end) {                        // next-window prefetch first
            int mn = end - nbase; if (mn > 64) mn = 64;
            if (lane < mn) pkn = spack[nbase + lane];
        }
        int j = 0;
        for (; j + 8 <= m; j += 8) {              // UNGUARDED: 8 gathers in flight
            unsigned int pp[8], vv[8];
            #pragma unroll
            for (int q = 0; q < 8; ++q)
                pp[q] = (unsigned int)__shfl((int)pk, j + q, 64);
            #pragma unroll
            for (int q = 0; q < 8; ++q)
                vv[q] = hb32[(size_t)(pp[q] & 0xffffu) * 64 + lane];
            #pragma unroll
            for (int q = 0; q < 8; ++q) CONSUME(pp[q], vv[q]);
        }
        for (; j < m; ++j) {                      // scalar tail (< 8 edges)
            unsigned int p1 = (unsigned int)__shfl((int)pk, j, 64);
            unsigned int v1 = hb32[(size_t)(p1 & 0xffffu) * 64 + lane];
            CONSUME(p1, v1);
        }
        base = nbase; pk = pkn;
        m = end - base; if (m > 64) m = 64;
    }
    if (curk >= 0) FLUSH();
    // zero rows for empty (dst,rel) segments (mean = 0)
    #pragma unroll 1
    for (int i = 0; i < 32; ++i) {
        if (!((flushed >> i) & 1u)) {
            int k = wid * 32 + i;
            int row = k >> 3;
            int c = (k & 7) * 16 + (lane >> 2);
            int swz = (c & ~7) | ((c ^ row) & 7);
            MtU[row * 512 + swz * 4 + (lane & 3)] = 0u;
        }
    }
    __syncthreads();   // the ONLY barrier: full 16x1024 mean tile ready

    // ---- slots 1..8: K=1024 MFMA sweep, A from swizzled LDS ----
    #pragma unroll
    for (int s = 1; s < 9; ++s) {
        const unsigned short* Wp = Wt2 + ((size_t)s * 128 + wid * 32 + l16) * DIM + quad * 8;
        bf16x8 b0[4], b1[4];
        #pragma unroll
        for (int kk = 0; kk < 4; ++kk) {
            b0[kk] = *(const bf16x8*)(Wp + kk * 32);
            b1[kk] = *(const bf16x8*)(Wp + 16 * DIM + kk * 32);
        }
        #pragma unroll
        for (int kk = 0; kk < 4; ++kk) {
            int c = (s - 1) * 16 + kk * 4 + quad;
            int swz = (c & ~7) | ((c ^ l16) & 7);
            bf16x8 af = *(const bf16x8*)&Mt[l16 * 1024 + swz * 8];
            acc[0] = __builtin_amdgcn_mfma_f32_16x16x32_bf16(af, b0[kk], acc[0], 0, 0, 0);
            acc[1] = __builtin_amdgcn_mfma_f32_16x16x32_bf16(af, b1[kk], acc[1], 0, 0, 0);
        }
    }

    // ---- epilogue: bias + relu + bf16 store (no guards: 3125*16 = 50000) ----
    // C/D layout: col = lane&15, row = (lane>>4)*4 + reg
    #pragma unroll
    for (int ni = 0; ni < 2; ++ni) {
        int gc = wid * 32 + ni * 16 + l16;
        float bv = bias[gc];
        #pragma unroll
        for (int rr = 0; rr < 4; ++rr) {
            int grow = t0 + quad * 4 + rr;
            hout[(size_t)grow * DIM + gc] = f2b(fmaxf(acc[ni][rr] + bv, 0.f));
        }
    }
}

// ---------------------------------------------------------------------------
// score: out[t] = sum_d h[head,d]*rel_emb[rel,d]*h[tail,d]  (h in bf16)
__global__ void score_kernel(const unsigned short* __restrict__ hb,
                             const float* __restrict__ rel_emb,
                             const int* __restrict__ head,
                             const int* __restrict__ rel,
                             const int* __restrict__ tail,
                             float* __restrict__ out) {
    int t = blockIdx.x * 4 + (threadIdx.x >> 6);
    if (t >= N_TRIP) return;
    int lane = threadIdx.x & 63;
    unsigned int ph = ((const unsigned int*)(hb + (size_t)head[t] * DIM))[lane];
    unsigned int pt = ((const unsigned int*)(hb + (size_t)tail[t] * DIM))[lane];
    float2 rr = ((const float2*)(rel_emb + (size_t)rel[t] * DIM))[lane];
    float s = blo(ph) * rr.x * blo(pt) + bhi(ph) * rr.y * bhi(pt);
    #pragma unroll
    for (int off = 32; off; off >>= 1) s += __shfl_xor(s, off, 64);
    if (lane == 0) out[t] = s;
}

// ---------------------------------------------------------------------------
extern "C" void kernel_launch(void* const* d_in, const int* in_sizes, int n_in,
                              void* d_out, int out_size, void* d_ws, size_t ws_size,
                              hipStream_t stream) {
    const float* emb     = (const float*)d_in[0];
    const float* W0      = (const float*)d_in[1];
    const float* root0   = (const float*)d_in[2];
    const float* b0      = (const float*)d_in[3];
    const float* W1      = (const float*)d_in[4];
    const float* root1   = (const float*)d_in[5];
    const float* b1      = (const float*)d_in[6];
    const float* rel_emb = (const float*)d_in[7];
    const int* edge_index = (const int*)d_in[8];
    const int* edge_type  = (const int*)d_in[9];
    const int* head_idx   = (const int*)d_in[10];
    const int* rel_idx    = (const int*)d_in[11];
    const int* tail_idx   = (const int*)d_in[12];
    float* out = (float*)d_out;

    // workspace layout (~48 MB, all disjoint, 16B-aligned chunks first):
    char* p = (char*)d_ws;
    size_t hb_bytes  = (size_t)N_NODES * DIM * sizeof(unsigned short);     // 12.8 MB
    size_t wt2_bytes = (size_t)9 * 128 * 128 * sizeof(unsigned short);     // 294912 B
    unsigned short* embb = (unsigned short*)p; p += hb_bytes;
    unsigned short* h1b  = (unsigned short*)p; p += hb_bytes;
    unsigned short* h2b  = (unsigned short*)p; p += hb_bytes;
    unsigned short* Wt2a = (unsigned short*)p; p += wt2_bytes;
    unsigned short* Wt2b = (unsigned short*)p; p += wt2_bytes;
    unsigned int* spack = (unsigned int*)p;   p += (size_t)N_EDGES * sizeof(unsigned int);
    unsigned int* slack = (unsigned int*)p;   p += (size_t)NBUCKET * CAP * sizeof(unsigned int);
    int* gcnt  = (int*)p;  p += (size_t)NBUCKET * sizeof(int);
    int* gbase = (int*)p;  p += (size_t)NBUCKET * sizeof(int);
    int* offsets = (int*)p;
    (void)ws_size; (void)in_sizes; (void)n_in; (void)out_size;

    dim3 blk256(256);

    // ---- 2-pass bucket sort of edges by (dst, rel), dst-major ----
    hipMemsetAsync(gcnt, 0, (size_t)NBUCKET * sizeof(int), stream);
    bucket_scatter<<<(N_EDGES + 4095) / 4096, blk256, 0, stream>>>(edge_index, edge_type,
                                                                   gcnt, slack);
    bucket_scan<<<1, 256, 0, stream>>>(gcnt, gbase, offsets);
    bucket_sort<<<NBUCKET, blk256, 0, stream>>>(slack, gcnt, gbase, spack, offsets);

    // ---- precision conversions ----
    cvt_emb_kernel<<<(N_NODES * DIM / 2 + 255) / 256, blk256, 0, stream>>>(emb, embb);
    cvt_w2_kernel<<<dim3(9, 128, 2), 128, 0, stream>>>(root0, W0, root1, W1, Wt2a, Wt2b);

    int fgrid = N_NODES / 16;   // 3125, exact

    // ---- fused layers: one-stream aggregation + single-barrier K=1152 MFMA ----
    rgcn_fused<<<fgrid, blk256, 0, stream>>>(embb, Wt2a, b0, offsets, spack, h1b);
    rgcn_fused<<<fgrid, blk256, 0, stream>>>(h1b, Wt2b, b1, offsets, spack, h2b);

    // ---- score ----
    score_kernel<<<(N_TRIP + 3) / 4, blk256, 0, stream>>>(h2b, rel_emb, head_idx, rel_idx,
                                                          tail_idx, out);
}